// Round 1
// baseline (18955.547 us; speedup 1.0000x reference)
//
#include <hip/hip_runtime.h>
#include <hip/hip_fp16.h>
#include <cmath>

// Problem constants (reference: B=256, T=512, IN=64, R=2048)
constexpr int kB  = 256;
constexpr int kT  = 512;
constexpr int kIN = 64;
constexpr int kR  = 2048;

typedef _Float16 f16x8 __attribute__((ext_vector_type(8)));
typedef float    f32x4 __attribute__((ext_vector_type(4)));

// LDS row stride in halfs: 64 + 8 pad -> row*144B, 16B-aligned (144=9*16),
// bank pattern gives only 2-way aliasing (free on gfx950, m136).
constexpr int kLds = 72;

// One recurrence step: s_out = tanh(X_t @ Win^T + s_in @ W^T)
// C-tile per block: 64 (batch) x 64 (r). Grid (R/64, B/64) = (32, 4).
// 256 threads = 4 waves; wave w owns rows [w*16, w*16+16), all 64 cols
// as 4 MFMA 16x16 tiles (shared a-frag across 4 b-frags).
__global__ __launch_bounds__(256) void esn_step(
    const _Float16* __restrict__ s_in,
    _Float16* __restrict__ s_out,
    const _Float16* __restrict__ Wh,    // [R, R] f16
    const _Float16* __restrict__ Winh,  // [R, IN] f16
    const float* __restrict__ X,        // [B, T, IN] fp32
    int t,
    float* __restrict__ outf)           // non-null on last step only
{
    __shared__ __align__(16) _Float16 As[64 * kLds];
    __shared__ __align__(16) _Float16 Bs[64 * kLds];

    const int tid  = threadIdx.x;
    const int wave = tid >> 6;
    const int lane = tid & 63;
    const int quad = lane >> 4;
    const int l16  = lane & 15;

    const int m0 = blockIdx.y * 64;  // batch band
    const int n0 = blockIdx.x * 64;  // r band

    f32x4 acc[4] = {};

    // ---- main K loop over W / s (K = 2048, BK = 64) ----
    for (int kt = 0; kt < kR / 64; ++kt) {
        const int k0 = kt * 64;
        __syncthreads();  // protect LDS from previous iter's readers
        // stage A (s rows) and B (W rows): 512 chunks of 8 halfs each
        for (int c = tid; c < 512; c += 256) {
            const int row  = c >> 3;
            const int col8 = (c & 7) << 3;
            uint4 va = *(const uint4*)(s_in + (size_t)(m0 + row) * kR + k0 + col8);
            *(uint4*)(&As[row * kLds + col8]) = va;
            uint4 vb = *(const uint4*)(Wh + (size_t)(n0 + row) * kR + k0 + col8);
            *(uint4*)(&Bs[row * kLds + col8]) = vb;
        }
        __syncthreads();
        #pragma unroll
        for (int kk = 0; kk < 64; kk += 32) {
            f16x8 a = *(const f16x8*)(&As[(wave * 16 + l16) * kLds + kk + quad * 8]);
            #pragma unroll
            for (int j = 0; j < 4; ++j) {
                f16x8 b = *(const f16x8*)(&Bs[(j * 16 + l16) * kLds + kk + quad * 8]);
                acc[j] = __builtin_amdgcn_mfma_f32_16x16x32_f16(a, b, acc[j], 0, 0, 0);
            }
        }
    }

    // ---- input-term tile: K = 64 over Win / x_t ----
    __syncthreads();
    for (int c = tid; c < 512; c += 256) {
        const int row  = c >> 3;
        const int col8 = (c & 7) << 3;
        const float* xp = X + ((size_t)(m0 + row) * kT + t) * kIN + col8;
        float4 f0 = *(const float4*)(xp);
        float4 f1 = *(const float4*)(xp + 4);
        _Float16 h[8] = {(_Float16)f0.x, (_Float16)f0.y, (_Float16)f0.z, (_Float16)f0.w,
                         (_Float16)f1.x, (_Float16)f1.y, (_Float16)f1.z, (_Float16)f1.w};
        *(uint4*)(&As[row * kLds + col8]) = *(const uint4*)h;
        uint4 vb = *(const uint4*)(Winh + (size_t)(n0 + row) * kIN + col8);
        *(uint4*)(&Bs[row * kLds + col8]) = vb;
    }
    __syncthreads();
    #pragma unroll
    for (int kk = 0; kk < 64; kk += 32) {
        f16x8 a = *(const f16x8*)(&As[(wave * 16 + l16) * kLds + kk + quad * 8]);
        #pragma unroll
        for (int j = 0; j < 4; ++j) {
            f16x8 b = *(const f16x8*)(&Bs[(j * 16 + l16) * kLds + kk + quad * 8]);
            acc[j] = __builtin_amdgcn_mfma_f32_16x16x32_f16(a, b, acc[j], 0, 0, 0);
        }
    }

    // ---- epilogue: tanh, write f16 state (+ fp32 final output) ----
    // D layout (16x16): col = lane&15, row = quad*4 + reg  [verified m89/m91]
    #pragma unroll
    for (int j = 0; j < 4; ++j) {
        #pragma unroll
        for (int i = 0; i < 4; ++i) {
            const int b = m0 + wave * 16 + quad * 4 + i;
            const int r = n0 + j * 16 + l16;
            const float v = tanhf(acc[j][i]);
            s_out[(size_t)b * kR + r] = (_Float16)v;
            if (outf) outf[(size_t)b * kR + r] = v;
        }
    }
}

// One-shot (per launch) fp32 -> f16 conversion of W and Win into workspace.
__global__ void convert_w(const float* __restrict__ W, const float* __restrict__ Win,
                          _Float16* __restrict__ Wh, _Float16* __restrict__ Winh)
{
    const size_t stride = (size_t)gridDim.x * blockDim.x;
    const size_t i0 = (size_t)blockIdx.x * blockDim.x + threadIdx.x;
    for (size_t i = i0; i < (size_t)kR * kR; i += stride) Wh[i] = (_Float16)W[i];
    for (size_t i = i0; i < (size_t)kR * kIN; i += stride) Winh[i] = (_Float16)Win[i];
}

extern "C" void kernel_launch(void* const* d_in, const int* in_sizes, int n_in,
                              void* d_out, int out_size, void* d_ws, size_t ws_size,
                              hipStream_t stream)
{
    const float* X   = (const float*)d_in[0];  // [B, T, IN]
    const float* Win = (const float*)d_in[1];  // [R, IN]
    const float* W   = (const float*)d_in[2];  // [R, R]
    float* out = (float*)d_out;                // [B, R]

    char* ws = (char*)d_ws;
    _Float16* Wh   = (_Float16*)ws;                                   // 8 MB
    _Float16* Winh = (_Float16*)(ws + (size_t)kR * kR * 2);           // 256 KB
    _Float16* sA   = (_Float16*)(ws + (size_t)kR * kR * 2 + (size_t)kR * kIN * 2);
    _Float16* sB   = sA + (size_t)kB * kR;                            // 1 MB each

    convert_w<<<1024, 256, 0, stream>>>(W, Win, Wh, Winh);
    hipMemsetAsync(sA, 0, (size_t)kB * kR * sizeof(_Float16), stream);

    dim3 grid(kR / 64, kB / 64);  // (32, 4) = 128 blocks
    for (int t = 0; t < kT; ++t) {
        const _Float16* sin_ = (t & 1) ? sB : sA;
        _Float16*       sout = (t & 1) ? sA : sB;
        esn_step<<<grid, 256, 0, stream>>>(sin_, sout, Wh, Winh, X, t,
                                           (t == kT - 1) ? out : nullptr);
    }
}